// Round 5
// baseline (252.893 us; speedup 1.0000x reference)
//
#include <hip/hip_runtime.h>
#include <math.h>

typedef _Float16 f16;
typedef _Float16 f16x4 __attribute__((ext_vector_type(4)));
typedef _Float16 f16x8 __attribute__((ext_vector_type(8)));
typedef float f32x16 __attribute__((ext_vector_type(16)));

#define MFMA_ __builtin_amdgcn_mfma_f32_32x32x16_f16
#define SLOPE_ 0.2f

constexpr int kB = 64, kT = 512, kD = 8, kH = 128, kE = 96;
constexpr int kFG = 145, kTM = 510, kN = kB * kTM;   // N = 32640 = 255*128

// fragment-linear weight images: frag fb=(c,t) is 64 lanes x 16 B contiguous.
// lane l of frag (c,t) holds W[t*32+(l&31)][c*16+(l>>5)*8 .. +7]
__device__ __forceinline__ f16x8 gfrag(const f16* img, int f, int lane) {
  return *(const f16x8*)(img + f*512 + lane*8);
}

// ---- build next-layer B-fragment from held quads via lane^32 exchange ------
// hq[tile][quad]: quad q holds act[n=lane&31][h = 32t + 8q + 4*(lane>>5) + e]
__device__ __forceinline__ f16x8 xfrag(const f16x4 (&hq)[4][4], int c, int h5) {
  const int t = c >> 1, p2 = (c & 1) * 2;
  f16x4 kq = h5 ? hq[t][p2+1] : hq[t][p2];
  f16x4 sq = h5 ? hq[t][p2]   : hq[t][p2+1];
  union { f16x4 v; unsigned int u[2]; } s, r;
  s.v = sq;
  r.u[0] = __shfl_xor(s.u[0], 32, 64);
  r.u[1] = __shfl_xor(s.u[1], 32, 64);
  f16x4 lo = h5 ? r.v : kq;
  f16x4 hi = h5 ? kq : r.v;
  union { f16x8 v8; f16x4 h[2]; } o;
  o.h[0] = lo; o.h[1] = hi;
  return o.v8;
}

// ========= weight pre-convert: f32 row-major -> f16 fragment-linear =========
// out elem e: j=e&7, l=(e>>3)&63, f=e>>9 (per d-slice), c=f>>2, t=f&3
// row = t*32+(l&31), col = c*16+(l>>5)*8+j ; src row stride SK, src col off 0.
template<int NF, int SK>
__device__ __forceinline__ void cvt_img(const float* __restrict__ src,
                                        f16* __restrict__ dst, int nd,
                                        int t0, int stride) {
  const int per_d = NF * 512;
  for (int e = t0; e < nd * per_d; e += stride) {
    int dd = e / per_d, r = e - dd * per_d;
    int f = r >> 9, l = (r >> 3) & 63, j = r & 7;
    int c = f >> 2, t = f & 3;
    int row = t*32 + (l & 31), col = c*16 + (l >> 5)*8 + j;
    dst[e] = (f16)src[((size_t)dd*kH + row)*SK + col];
  }
}

__global__ __launch_bounds__(256) void cvt_kernel(
    const float* __restrict__ gW0, const float* __restrict__ gW1,
    const float* __restrict__ gW2,
    const float* __restrict__ fcW0, const float* __restrict__ fcW1,
    const float* __restrict__ fcWf,
    f16* __restrict__ W0img, f16* __restrict__ W1img, f16* __restrict__ W2img,
    f16* __restrict__ fW0img, f16* __restrict__ fW1img, f16* __restrict__ fWfimg)
{
  const int stride = gridDim.x * 256;
  const int t0 = blockIdx.x*256 + threadIdx.x;
  cvt_img<36, kFG>(gW0, W0img, kD, t0, stride);   // g L0 (cols 0..143 of 145)
  cvt_img<32, kH >(gW1, W1img, kD, t0, stride);
  cvt_img<32, kH >(gW2, W2img, kD, t0, stride);
  cvt_img<24, kE >(fcW0, fW0img, 1, t0, stride);
  cvt_img<32, kH >(fcW1, fW1img, 1, t0, stride);
  cvt_img<32, kH >(fcWf, fWfimg, 1, t0, stride);
}

// ===== fc_mlp: emb(N,96) -> embh(N,128) f16; barrier-free indep waves =======
__global__ __launch_bounds__(256, 2) void fc_kernel(
    const float* __restrict__ emb,
    const f16* __restrict__ W0i, const float* __restrict__ b0,
    const f16* __restrict__ W1i, const float* __restrict__ b1,
    const f16* __restrict__ Wfi, const float* __restrict__ bf,
    f16* __restrict__ out)
{
  __shared__ float lb0[kH], lb1[kH], lbf[kH];
  const int bn = blockIdx.x * 128;
  const int tid = threadIdx.x, wave = tid >> 6, lane = tid & 63;
  const int l31 = lane & 31, h5 = lane >> 5;
  const int n = bn + wave*32 + l31;

  if (tid < kH) { lb0[tid] = b0[tid]; lb1[tid] = b1[tid]; lbf[tid] = bf[tid]; }
  __syncthreads();

  f32x16 zero = {};
  f32x16 acc[4] = {zero, zero, zero, zero};
  const float* erow = emb + (size_t)n*kE + h5*8;
  #pragma unroll
  for (int c = 0; c < 6; ++c) {
    float4 a = *(const float4*)(erow + c*16);
    float4 b = *(const float4*)(erow + c*16 + 4);
    f16x8 v;
    v[0]=(f16)a.x; v[1]=(f16)a.y; v[2]=(f16)a.z; v[3]=(f16)a.w;
    v[4]=(f16)b.x; v[5]=(f16)b.y; v[6]=(f16)b.z; v[7]=(f16)b.w;
    #pragma unroll
    for (int t = 0; t < 4; ++t)
      acc[t] = MFMA_(gfrag(W0i, c*4+t, lane), v, acc[t], 0, 0, 0);
  }

  f16x4 hP[4][4];
  #pragma unroll
  for (int t = 0; t < 4; ++t)
    #pragma unroll
    for (int q = 0; q < 4; ++q) {
      float4 b4 = *(const float4*)&lb0[t*32 + q*8 + h5*4];
      const float* bp = (const float*)&b4;
      f16x4 v;
      #pragma unroll
      for (int e = 0; e < 4; ++e) {
        float z = acc[t][q*4+e] + bp[e];
        v[e] = (f16)fmaxf(z, SLOPE_*z);
      }
      hP[t][q] = v;
    }

  #pragma unroll
  for (int t = 0; t < 4; ++t) acc[t] = zero;
  #pragma unroll
  for (int c = 0; c < 8; ++c) {
    f16x8 bP = xfrag(hP, c, h5);
    #pragma unroll
    for (int t = 0; t < 4; ++t)
      acc[t] = MFMA_(gfrag(W1i, c*4+t, lane), bP, acc[t], 0, 0, 0);
  }
  #pragma unroll
  for (int t = 0; t < 4; ++t)
    #pragma unroll
    for (int q = 0; q < 4; ++q) {
      float4 b4 = *(const float4*)&lb1[t*32 + q*8 + h5*4];
      const float* bp = (const float*)&b4;
      f16x4 v;
      #pragma unroll
      for (int e = 0; e < 4; ++e) {
        float z = acc[t][q*4+e] + bp[e];
        v[e] = (f16)fmaxf(z, SLOPE_*z);
      }
      hP[t][q] = v;
    }

  f32x16 accf[4] = {zero, zero, zero, zero};
  #pragma unroll
  for (int c = 0; c < 8; ++c) {
    f16x8 bP = xfrag(hP, c, h5);
    #pragma unroll
    for (int t = 0; t < 4; ++t)
      accf[t] = MFMA_(gfrag(Wfi, c*4+t, lane), bP, accf[t], 0, 0, 0);
  }
  #pragma unroll
  for (int t = 0; t < 4; ++t)
    #pragma unroll
    for (int q = 0; q < 4; ++q) {
      float4 b4 = *(const float4*)&lbf[t*32 + q*8 + h5*4];
      const float* bp = (const float*)&b4;
      f16x4 v;
      #pragma unroll
      for (int e = 0; e < 4; ++e) v[e] = (f16)(accf[t][q*4+e] + bp[e]);
      hP[t][q] = v;
    }
  #pragma unroll
  for (int c = 0; c < 8; ++c) {
    f16x8 v = xfrag(hP, c, h5);
    *(f16x8*)(out + (size_t)n*kH + c*16 + h5*8) = v;
  }
}

// ==== g_mlp fwd + JVP: weights global->regs, register-chained, fused ========
__global__ __launch_bounds__(256, 2) void g_kernel(
    const float* __restrict__ x, const f16* __restrict__ embh,
    const f16* __restrict__ W0img, const f16* __restrict__ W1img,
    const f16* __restrict__ W2img,
    const float* __restrict__ gW0f32,
    const float* __restrict__ gb0, const float* __restrict__ gb1,
    const float* __restrict__ gb2, const float* __restrict__ gWf,
    const float* __restrict__ gbf,
    float* __restrict__ resid, float* __restrict__ logdet)
{
  __shared__ float lwf[kH], lw144[kH], lb0[kH], lb1[kH], lb2[kH];
  __shared__ float part[8];

  const int d = blockIdx.y, bn = blockIdx.x * 128;
  const int tid = threadIdx.x, wave = tid >> 6, lane = tid & 63;
  const int l31 = lane & 31, h5 = lane >> 5;
  const int n = bn + wave*32 + l31;
  const int b = n / kTM, tt = n - b*kTM;

  if (tid < kH) {
    lwf[tid]   = gWf[d*kH + tid];
    lw144[tid] = gW0f32[(d*kH + tid)*kFG + 144];
    lb0[tid]   = gb0[d*kH + tid];
    lb1[tid]   = gb1[d*kH + tid];
    lb2[tid]   = gb2[d*kH + tid];
  }
  __syncthreads();

  const f16* W0d = W0img + d*36*512;
  const f16* W1d = W1img + d*32*512;
  const f16* W2d = W2img + d*32*512;

  // yy B-frag (chunk 8): k = 128 + h5*8 + j -> x[b, tt+h5, j]
  const float* xp = x + ((size_t)b*kT + tt + h5)*kD;
  float4 xa = *(const float4*)xp;
  float4 xb = *(const float4*)(xp + 4);
  f16x8 f8;
  f8[0]=(f16)xa.x; f8[1]=(f16)xa.y; f8[2]=(f16)xa.z; f8[3]=(f16)xa.w;
  f8[4]=(f16)xb.x; f8[5]=(f16)xb.y; f8[6]=(f16)xb.z; f8[7]=(f16)xb.w;
  const float xxv = x[((size_t)b*kT + tt + 2)*kD + d];

  f32x16 zero = {};
  f32x16 accP[4] = {zero, zero, zero, zero};
  f32x16 accT[4] = {zero, zero, zero, zero};

  // ---- L0 (primal only; tangent seed = w144*mask in epilogue)
  const f16* erow = embh + (size_t)n*kH + h5*8;
  #pragma unroll
  for (int c = 0; c < 8; ++c) {
    f16x8 bF = *(const f16x8*)(erow + c*16);
    #pragma unroll
    for (int t = 0; t < 4; ++t)
      accP[t] = MFMA_(gfrag(W0d, c*4+t, lane), bF, accP[t], 0, 0, 0);
  }
  #pragma unroll
  for (int t = 0; t < 4; ++t)
    accP[t] = MFMA_(gfrag(W0d, 32+t, lane), f8, accP[t], 0, 0, 0);

  f16x4 hP[4][4], hT[4][4];
  #pragma unroll
  for (int t = 0; t < 4; ++t)
    #pragma unroll
    for (int q = 0; q < 4; ++q) {
      float4 w4 = *(const float4*)&lw144[t*32 + q*8 + h5*4];
      float4 b4 = *(const float4*)&lb0[t*32 + q*8 + h5*4];
      const float* wp = (const float*)&w4;
      const float* bp = (const float*)&b4;
      f16x4 vp, vt;
      #pragma unroll
      for (int e = 0; e < 4; ++e) {
        float z = accP[t][q*4+e] + xxv*wp[e] + bp[e];
        vp[e] = (f16)fmaxf(z, SLOPE_*z);
        vt[e] = (f16)((z >= 0.f) ? wp[e] : SLOPE_*wp[e]);
      }
      hP[t][q] = vp; hT[t][q] = vt;
    }

  // ---- L1 (primal + tangent share A-frags)
  #pragma unroll
  for (int t = 0; t < 4; ++t) { accP[t] = zero; accT[t] = zero; }
  #pragma unroll
  for (int c = 0; c < 8; ++c) {
    f16x8 bP = xfrag(hP, c, h5);
    f16x8 bT = xfrag(hT, c, h5);
    #pragma unroll
    for (int t = 0; t < 4; ++t) {
      f16x8 a = gfrag(W1d, c*4+t, lane);
      accP[t] = MFMA_(a, bP, accP[t], 0, 0, 0);
      accT[t] = MFMA_(a, bT, accT[t], 0, 0, 0);
    }
  }
  #pragma unroll
  for (int t = 0; t < 4; ++t)
    #pragma unroll
    for (int q = 0; q < 4; ++q) {
      float4 b4 = *(const float4*)&lb1[t*32 + q*8 + h5*4];
      const float* bp = (const float*)&b4;
      f16x4 vp, vt;
      #pragma unroll
      for (int e = 0; e < 4; ++e) {
        float z = accP[t][q*4+e] + bp[e];
        float tv = accT[t][q*4+e];
        vp[e] = (f16)fmaxf(z, SLOPE_*z);
        vt[e] = (f16)((z >= 0.f) ? tv : SLOPE_*tv);
      }
      hP[t][q] = vp; hT[t][q] = vt;
    }

  // ---- L2
  #pragma unroll
  for (int t = 0; t < 4; ++t) { accP[t] = zero; accT[t] = zero; }
  #pragma unroll
  for (int c = 0; c < 8; ++c) {
    f16x8 bP = xfrag(hP, c, h5);
    f16x8 bT = xfrag(hT, c, h5);
    #pragma unroll
    for (int t = 0; t < 4; ++t) {
      f16x8 a = gfrag(W2d, c*4+t, lane);
      accP[t] = MFMA_(a, bP, accP[t], 0, 0, 0);
      accT[t] = MFMA_(a, bT, accT[t], 0, 0, 0);
    }
  }

  // ---- final epilogue + dot with wf
  float p = 0.f, tp = 0.f;
  #pragma unroll
  for (int t = 0; t < 4; ++t)
    #pragma unroll
    for (int q = 0; q < 4; ++q) {
      float4 b4 = *(const float4*)&lb2[t*32 + q*8 + h5*4];
      float4 w4 = *(const float4*)&lwf[t*32 + q*8 + h5*4];
      const float* bp = (const float*)&b4;
      const float* wp = (const float*)&w4;
      #pragma unroll
      for (int e = 0; e < 4; ++e) {
        float z = accP[t][q*4+e] + bp[e];
        float tv = accT[t][q*4+e];
        float zl = fmaxf(z, SLOPE_*z);
        float tl = (z >= 0.f) ? tv : SLOPE_*tv;
        p  = fmaf(zl, wp[e], p);
        tp = fmaf(tl, wp[e], tp);
      }
    }
  p  += __shfl_xor(p, 32, 64);
  tp += __shfl_xor(tp, 32, 64);

  float llog = 0.f;
  if (!h5) {
    resid[(size_t)n*kD + d] = p + gbf[d];
    llog = logf(fabsf(tp));
  }
  // block partial of logdet, segmented over the (at most 2) batches it spans
  const int bfirst = bn / kTM;
  float s0 = (b == bfirst) ? llog : 0.f;
  float s1 = llog - s0;
  #pragma unroll
  for (int off = 32; off > 0; off >>= 1) {
    s0 += __shfl_down(s0, off, 64);
    s1 += __shfl_down(s1, off, 64);
  }
  if (lane == 0) { part[wave*2] = s0; part[wave*2 + 1] = s1; }
  __syncthreads();
  if (tid == 0) {
    float S0 = part[0] + part[2] + part[4] + part[6];
    float S1 = part[1] + part[3] + part[5] + part[7];
    atomicAdd(&logdet[bfirst], S0);
    if (S1 != 0.f) atomicAdd(&logdet[bfirst + 1], S1);
  }
}

extern "C" void kernel_launch(void* const* d_in, const int* in_sizes, int n_in,
                              void* d_out, int out_size, void* d_ws, size_t ws_size,
                              hipStream_t stream) {
  const float* x    = (const float*)d_in[0];
  const float* emb  = (const float*)d_in[1];
  const float* fcW0 = (const float*)d_in[2];
  const float* fcb0 = (const float*)d_in[3];
  const float* fcW1 = (const float*)d_in[4];
  const float* fcb1 = (const float*)d_in[5];
  const float* fcWf = (const float*)d_in[6];
  const float* fcbf = (const float*)d_in[7];
  const float* gW0  = (const float*)d_in[8];
  const float* gb0  = (const float*)d_in[9];
  const float* gW1  = (const float*)d_in[10];
  const float* gb1  = (const float*)d_in[11];
  const float* gW2  = (const float*)d_in[12];
  const float* gb2  = (const float*)d_in[13];
  const float* gWf  = (const float*)d_in[14];
  const float* gbf  = (const float*)d_in[15];
  float* out = (float*)d_out;
  float* logdet = out + (size_t)kN * kD;

  char* ws = (char*)d_ws;
  f16* embh   = (f16*)ws;   ws += (size_t)kN*kH*2;
  f16* W0img  = (f16*)ws;   ws += (size_t)kD*36*512*2;
  f16* W1img  = (f16*)ws;   ws += (size_t)kD*32*512*2;
  f16* W2img  = (f16*)ws;   ws += (size_t)kD*32*512*2;
  f16* fW0img = (f16*)ws;   ws += (size_t)24*512*2;
  f16* fW1img = (f16*)ws;   ws += (size_t)32*512*2;
  f16* fWfimg = (f16*)ws;

  cvt_kernel<<<256, 256, 0, stream>>>(gW0, gW1, gW2, fcW0, fcW1, fcWf,
                                      W0img, W1img, W2img,
                                      fW0img, fW1img, fWfimg);
  fc_kernel<<<kN/128, 256, 0, stream>>>(emb, fW0img, fcb0, fW1img, fcb1,
                                        fWfimg, fcbf, embh);
  hipMemsetAsync((void*)logdet, 0, kB*sizeof(float), stream);
  g_kernel<<<dim3(kN/128, kD), 256, 0, stream>>>(
      x, embh, W0img, W1img, W2img, gW0, gb0, gb1, gb2, gWf, gbf,
      out, logdet);
}

// Round 6
// 163.872 us; speedup vs baseline: 1.5432x; 1.5432x over previous
//
#include <hip/hip_runtime.h>
#include <math.h>

typedef _Float16 f16;
typedef _Float16 f16x8 __attribute__((ext_vector_type(8)));
typedef float f32x16 __attribute__((ext_vector_type(16)));

#define MFMA_ __builtin_amdgcn_mfma_f32_32x32x16_f16
#define SLOPE_ 0.2f

constexpr int kB = 64, kT = 512, kD = 8, kH = 128, kE = 96;
constexpr int kFG = 145, kTM = 510, kN = kB * kTM;   // 32640 = 255*128

// k-permutation absorbed into weight images so next-layer B-fragments are the
// held C/D quads verbatim: pi(16c+8s+j) = 32(c>>1)+16(c&1)+8(j>>2)+4s+(j&3)
__device__ __forceinline__ int pif(int k) {
  if (k >= 128) return k;                     // g L0 yy region stays canonical
  int c = k >> 4, s = (k >> 3) & 1, j = k & 7;
  return ((c >> 1) << 5) | ((c & 1) << 4) | ((j >> 2) << 3) | (s << 2) | (j & 3);
}

// fragment-linear images: frag f = 64 lanes x 16 B contiguous.
__device__ __forceinline__ f16x8 gfrag(const f16* img, int f, int lane) {
  return *(const f16x8*)(img + f*512 + lane*8);
}

// ========= weight pre-convert: f32 row-major -> f16 fragment-linear =========
template<int NF, int SK, int PERM>
__device__ __forceinline__ void cvt_img(const float* __restrict__ src,
                                        f16* __restrict__ dst, int nd,
                                        int t0, int stride) {
  const int per_d = NF * 512;
  for (int e = t0; e < nd * per_d; e += stride) {
    int dd = e / per_d, r = e - dd * per_d;
    int f = r >> 9, l = (r >> 3) & 63, j = r & 7;
    int c = f >> 2, t = f & 3;
    int row = t*32 + (l & 31);
    int col = c*16 + ((l >> 5) << 3) + j;
    if (PERM) col = pif(col);
    dst[e] = (f16)src[((size_t)dd*kH + row)*SK + col];
  }
}

__global__ __launch_bounds__(256) void cvt_kernel(
    const float* __restrict__ gW0, const float* __restrict__ gW1,
    const float* __restrict__ gW2,
    const float* __restrict__ fcW0, const float* __restrict__ fcW1,
    const float* __restrict__ fcWf,
    f16* __restrict__ W0img, f16* __restrict__ W1img, f16* __restrict__ W2img,
    f16* __restrict__ fW0img, f16* __restrict__ fW1img, f16* __restrict__ fWfimg,
    float* __restrict__ w144buf, float* __restrict__ logdet)
{
  const int stride = gridDim.x * 256;
  const int t0 = blockIdx.x*256 + threadIdx.x;
  cvt_img<36, kFG, 1>(gW0, W0img, kD, t0, stride);
  cvt_img<32, kH , 1>(gW1, W1img, kD, t0, stride);
  cvt_img<32, kH , 1>(gW2, W2img, kD, t0, stride);
  cvt_img<24, kE , 0>(fcW0, fW0img, 1, t0, stride);
  cvt_img<32, kH , 1>(fcW1, fW1img, 1, t0, stride);
  cvt_img<32, kH , 1>(fcWf, fWfimg, 1, t0, stride);
  for (int i = t0; i < kD*kH; i += stride)
    w144buf[i] = gW0[(size_t)i*kFG + 144];
  if (t0 < kB) logdet[t0] = 0.f;
}

// ===== fc_mlp: emb(N,96) -> embh'(N,128) f16 (pi-ordered); 1 barrier ========
__global__ __launch_bounds__(256, 2) void fc_kernel(
    const float* __restrict__ emb,
    const f16* __restrict__ fW0, const f16* __restrict__ fW1,
    const f16* __restrict__ fWf,
    const float* __restrict__ b0, const float* __restrict__ b1,
    const float* __restrict__ bf, f16* __restrict__ out)
{
  __shared__ f16 wbuf[62*512];                 // fW1 frags 0..31, fWf frags 0..29
  const int bn = blockIdx.x * 128;
  const int tid = threadIdx.x, wave = tid >> 6, lane = tid & 63;
  const int l31 = lane & 31, h5 = lane >> 5;
  const int n = bn + wave*32 + l31;

  #pragma unroll
  for (int i = 0; i < 8; ++i) {
    f16x8 v = *(const f16x8*)(fW1 + (size_t)(tid + i*256)*8);
    *(f16x8*)(wbuf + (tid + i*256)*8) = v;
  }
  #pragma unroll
  for (int i = 0; i < 8; ++i) {
    int idx = tid + i*256;
    if (idx < 1920) {
      f16x8 v = *(const f16x8*)(fWf + (size_t)idx*8);
      *(f16x8*)(wbuf + (2048 + idx)*8) = v;
    }
  }

  const float* erow = emb + (size_t)n*kE + h5*8;
  f16x8 embF[6];
  #pragma unroll
  for (int c = 0; c < 6; ++c) {
    float4 a = *(const float4*)(erow + c*16);
    float4 b = *(const float4*)(erow + c*16 + 4);
    f16x8 v;
    v[0]=(f16)a.x; v[1]=(f16)a.y; v[2]=(f16)a.z; v[3]=(f16)a.w;
    v[4]=(f16)b.x; v[5]=(f16)b.y; v[6]=(f16)b.z; v[7]=(f16)b.w;
    embF[c] = v;
  }
  __syncthreads();                              // B1: wbuf ready

  f32x16 zero = {};
  f32x16 acc[4] = {zero, zero, zero, zero};
  #pragma unroll
  for (int c = 0; c < 6; ++c)
    #pragma unroll
    for (int t = 0; t < 4; ++t)
      acc[t] = MFMA_(gfrag(fW0, c*4+t, lane), embF[c], acc[t], 0, 0, 0);

  f16x8 hq[4][2];
  #pragma unroll
  for (int t = 0; t < 4; ++t)
    #pragma unroll
    for (int q = 0; q < 4; ++q) {
      float4 b4 = *(const float4*)(b0 + t*32 + q*8 + h5*4);
      const float* bp = (const float*)&b4;
      #pragma unroll
      for (int e = 0; e < 4; ++e) {
        float z = acc[t][q*4+e] + bp[e];
        hq[t][q>>1][(q&1)*4+e] = (f16)fmaxf(z, SLOPE_*z);
      }
    }

  #pragma unroll
  for (int t = 0; t < 4; ++t) acc[t] = zero;
  #pragma unroll
  for (int c = 0; c < 8; ++c) {
    f16x8 bP = hq[c>>1][c&1];
    #pragma unroll
    for (int t = 0; t < 4; ++t) {
      f16x8 a = *(const f16x8*)(wbuf + (c*4+t)*512 + lane*8);
      acc[t] = MFMA_(a, bP, acc[t], 0, 0, 0);
    }
  }
  #pragma unroll
  for (int t = 0; t < 4; ++t)
    #pragma unroll
    for (int q = 0; q < 4; ++q) {
      float4 b4 = *(const float4*)(b1 + t*32 + q*8 + h5*4);
      const float* bp = (const float*)&b4;
      #pragma unroll
      for (int e = 0; e < 4; ++e) {
        float z = acc[t][q*4+e] + bp[e];
        hq[t][q>>1][(q&1)*4+e] = (f16)fmaxf(z, SLOPE_*z);
      }
    }

  #pragma unroll
  for (int t = 0; t < 4; ++t) acc[t] = zero;
  #pragma unroll
  for (int c = 0; c < 8; ++c) {
    f16x8 bP = hq[c>>1][c&1];
    #pragma unroll
    for (int t = 0; t < 4; ++t) {
      int f = c*4 + t;
      f16x8 a = (f < 30) ? *(const f16x8*)(wbuf + (32 + f)*512 + lane*8)
                         : gfrag(fWf, f, lane);
      acc[t] = MFMA_(a, bP, acc[t], 0, 0, 0);
    }
  }
  #pragma unroll
  for (int t = 0; t < 4; ++t)
    #pragma unroll
    for (int q = 0; q < 4; ++q) {
      float4 b4 = *(const float4*)(bf + t*32 + q*8 + h5*4);
      const float* bp = (const float*)&b4;
      #pragma unroll
      for (int e = 0; e < 4; ++e)
        hq[t][q>>1][(q&1)*4+e] = (f16)(acc[t][q*4+e] + bp[e]);
    }
  #pragma unroll
  for (int c = 0; c < 8; ++c)
    *(f16x8*)(out + (size_t)n*kH + c*16 + h5*8) = hq[c>>1][c&1];
}

// ==== g_mlp fwd + JVP: pi-chained registers, W1/W2 in LDS, fused logdet =====
__global__ __launch_bounds__(256, 2) void g_kernel(
    const float* __restrict__ x, const f16* __restrict__ embh,
    const f16* __restrict__ W0img, const f16* __restrict__ W1img,
    const f16* __restrict__ W2img,
    const float* __restrict__ w144buf,
    const float* __restrict__ gb0, const float* __restrict__ gb1,
    const float* __restrict__ gb2, const float* __restrict__ gWf,
    const float* __restrict__ gbf,
    float* __restrict__ resid, float* __restrict__ logdet)
{
  __shared__ f16 wbuf[62*512];                 // W1 frags 0..31, W2 frags 0..29
  __shared__ float part[8];
  const int d = blockIdx.y, bn = blockIdx.x * 128;
  const int tid = threadIdx.x, wave = tid >> 6, lane = tid & 63;
  const int l31 = lane & 31, h5 = lane >> 5;
  const int n = bn + wave*32 + l31;
  const int b = n / kTM, tt = n - b*kTM;

  const f16* W0d = W0img + d*36*512;
  const f16* W1d = W1img + d*32*512;
  const f16* W2d = W2img + d*32*512;

  #pragma unroll
  for (int i = 0; i < 8; ++i) {
    f16x8 v = *(const f16x8*)(W1d + (size_t)(tid + i*256)*8);
    *(f16x8*)(wbuf + (tid + i*256)*8) = v;
  }
  #pragma unroll
  for (int i = 0; i < 8; ++i) {
    int idx = tid + i*256;
    if (idx < 1920) {
      f16x8 v = *(const f16x8*)(W2d + (size_t)idx*8);
      *(f16x8*)(wbuf + (2048 + idx)*8) = v;
    }
  }

  // L0 B-frags: embh' rows (pi-ordered) + yy from x + xx scalar
  const f16* erow = embh + (size_t)n*kH + h5*8;
  f16x8 embF[8];
  #pragma unroll
  for (int c = 0; c < 8; ++c) embF[c] = *(const f16x8*)(erow + c*16);
  const float* xp = x + ((size_t)b*kT + tt + h5)*kD;
  float4 xa = *(const float4*)xp;
  float4 xb = *(const float4*)(xp + 4);
  f16x8 f8;
  f8[0]=(f16)xa.x; f8[1]=(f16)xa.y; f8[2]=(f16)xa.z; f8[3]=(f16)xa.w;
  f8[4]=(f16)xb.x; f8[5]=(f16)xb.y; f8[6]=(f16)xb.z; f8[7]=(f16)xb.w;
  const float xxv = x[((size_t)b*kT + tt + 2)*kD + d];
  __syncthreads();                              // B1: wbuf ready

  f32x16 zero = {};
  f32x16 accP[4] = {zero, zero, zero, zero};
  f32x16 accT[4] = {zero, zero, zero, zero};

  // ---- L0: W0 frags direct-global (36), primal only
  #pragma unroll
  for (int c = 0; c < 8; ++c)
    #pragma unroll
    for (int t = 0; t < 4; ++t)
      accP[t] = MFMA_(gfrag(W0d, c*4+t, lane), embF[c], accP[t], 0, 0, 0);
  #pragma unroll
  for (int t = 0; t < 4; ++t)
    accP[t] = MFMA_(gfrag(W0d, 32+t, lane), f8, accP[t], 0, 0, 0);

  f16x8 hqP[4][2], hqT[4][2];
  #pragma unroll
  for (int t = 0; t < 4; ++t)
    #pragma unroll
    for (int q = 0; q < 4; ++q) {
      float4 w4 = *(const float4*)(w144buf + d*kH + t*32 + q*8 + h5*4);
      float4 b4 = *(const float4*)(gb0 + d*kH + t*32 + q*8 + h5*4);
      const float* wp = (const float*)&w4;
      const float* bp = (const float*)&b4;
      #pragma unroll
      for (int e = 0; e < 4; ++e) {
        float z = accP[t][q*4+e] + xxv*wp[e] + bp[e];
        float m = (z >= 0.f) ? 1.f : SLOPE_;
        hqP[t][q>>1][(q&1)*4+e] = (f16)(z*m);
        hqT[t][q>>1][(q&1)*4+e] = (f16)(wp[e]*m);
      }
    }

  // ---- L1 (LDS frags 0..31), primal + tangent share A-frags
  #pragma unroll
  for (int t = 0; t < 4; ++t) { accP[t] = zero; accT[t] = zero; }
  #pragma unroll
  for (int c = 0; c < 8; ++c) {
    f16x8 bP = hqP[c>>1][c&1];
    f16x8 bT = hqT[c>>1][c&1];
    #pragma unroll
    for (int t = 0; t < 4; ++t) {
      f16x8 a = *(const f16x8*)(wbuf + (c*4+t)*512 + lane*8);
      accP[t] = MFMA_(a, bP, accP[t], 0, 0, 0);
      accT[t] = MFMA_(a, bT, accT[t], 0, 0, 0);
    }
  }
  #pragma unroll
  for (int t = 0; t < 4; ++t)
    #pragma unroll
    for (int q = 0; q < 4; ++q) {
      float4 b4 = *(const float4*)(gb1 + d*kH + t*32 + q*8 + h5*4);
      const float* bp = (const float*)&b4;
      #pragma unroll
      for (int e = 0; e < 4; ++e) {
        float z = accP[t][q*4+e] + bp[e];
        float tv = accT[t][q*4+e];
        float m = (z >= 0.f) ? 1.f : SLOPE_;
        hqP[t][q>>1][(q&1)*4+e] = (f16)(z*m);
        hqT[t][q>>1][(q&1)*4+e] = (f16)(tv*m);
      }
    }

  // ---- L2 (LDS frags 32..61; frags 30/31 direct-global)
  #pragma unroll
  for (int t = 0; t < 4; ++t) { accP[t] = zero; accT[t] = zero; }
  #pragma unroll
  for (int c = 0; c < 8; ++c) {
    f16x8 bP = hqP[c>>1][c&1];
    f16x8 bT = hqT[c>>1][c&1];
    #pragma unroll
    for (int t = 0; t < 4; ++t) {
      int f = c*4 + t;
      f16x8 a = (f < 30) ? *(const f16x8*)(wbuf + (32 + f)*512 + lane*8)
                         : gfrag(W2d, f, lane);
      accP[t] = MFMA_(a, bP, accP[t], 0, 0, 0);
      accT[t] = MFMA_(a, bT, accT[t], 0, 0, 0);
    }
  }

  // ---- final epilogue + dot with wf (C/D space, broadcast loads)
  float p = 0.f, tp = 0.f;
  #pragma unroll
  for (int t = 0; t < 4; ++t)
    #pragma unroll
    for (int q = 0; q < 4; ++q) {
      float4 b4 = *(const float4*)(gb2 + d*kH + t*32 + q*8 + h5*4);
      float4 w4 = *(const float4*)(gWf + d*kH + t*32 + q*8 + h5*4);
      const float* bp = (const float*)&b4;
      const float* wp = (const float*)&w4;
      #pragma unroll
      for (int e = 0; e < 4; ++e) {
        float z = accP[t][q*4+e] + bp[e];
        float tv = accT[t][q*4+e];
        float zl = fmaxf(z, SLOPE_*z);
        float tl = (z >= 0.f) ? tv : SLOPE_*tv;
        p  = fmaf(zl, wp[e], p);
        tp = fmaf(tl, wp[e], tp);
      }
    }
  p  += __shfl_xor(p, 32, 64);
  tp += __shfl_xor(tp, 32, 64);

  float llog = 0.f;
  if (!h5) {
    resid[(size_t)n*kD + d] = p + gbf[d];
    llog = logf(fabsf(tp));
  }
  const int bfirst = bn / kTM;
  float s0 = (b == bfirst) ? llog : 0.f;
  float s1 = llog - s0;
  #pragma unroll
  for (int off = 32; off > 0; off >>= 1) {
    s0 += __shfl_down(s0, off, 64);
    s1 += __shfl_down(s1, off, 64);
  }
  if (lane == 0) { part[wave*2] = s0; part[wave*2 + 1] = s1; }
  __syncthreads();                              // B2
  if (tid == 0) {
    float S0 = part[0] + part[2] + part[4] + part[6];
    float S1 = part[1] + part[3] + part[5] + part[7];
    atomicAdd(&logdet[bfirst], S0);
    if (S1 != 0.f) atomicAdd(&logdet[bfirst + 1], S1);
  }
}

extern "C" void kernel_launch(void* const* d_in, const int* in_sizes, int n_in,
                              void* d_out, int out_size, void* d_ws, size_t ws_size,
                              hipStream_t stream) {
  const float* x    = (const float*)d_in[0];
  const float* emb  = (const float*)d_in[1];
  const float* fcW0 = (const float*)d_in[2];
  const float* fcb0 = (const float*)d_in[3];
  const float* fcW1 = (const float*)d_in[4];
  const float* fcb1 = (const float*)d_in[5];
  const float* fcWf = (const float*)d_in[6];
  const float* fcbf = (const float*)d_in[7];
  const float* gW0  = (const float*)d_in[8];
  const float* gb0  = (const float*)d_in[9];
  const float* gW1  = (const float*)d_in[10];
  const float* gb1  = (const float*)d_in[11];
  const float* gW2  = (const float*)d_in[12];
  const float* gb2  = (const float*)d_in[13];
  const float* gWf  = (const float*)d_in[14];
  const float* gbf  = (const float*)d_in[15];
  float* out = (float*)d_out;
  float* logdet = out + (size_t)kN * kD;

  char* ws = (char*)d_ws;
  f16*   embh    = (f16*)ws;    ws += (size_t)kN*kH*2;
  f16*   W0img   = (f16*)ws;    ws += (size_t)kD*36*512*2;
  f16*   W1img   = (f16*)ws;    ws += (size_t)kD*32*512*2;
  f16*   W2img   = (f16*)ws;    ws += (size_t)kD*32*512*2;
  f16*   fW0img  = (f16*)ws;    ws += (size_t)24*512*2;
  f16*   fW1img  = (f16*)ws;    ws += (size_t)32*512*2;
  f16*   fWfimg  = (f16*)ws;    ws += (size_t)32*512*2;
  float* w144buf = (float*)ws;

  cvt_kernel<<<256, 256, 0, stream>>>(gW0, gW1, gW2, fcW0, fcW1, fcWf,
                                      W0img, W1img, W2img,
                                      fW0img, fW1img, fWfimg,
                                      w144buf, logdet);
  fc_kernel<<<kN/128, 256, 0, stream>>>(emb, fW0img, fW1img, fWfimg,
                                        fcb0, fcb1, fcbf, embh);
  g_kernel<<<dim3(kN/128, kD), 256, 0, stream>>>(
      x, embh, W0img, W1img, W2img, w144buf,
      gb0, gb1, gb2, gWf, gbf, out, logdet);
}